// Round 5
// baseline (2380.695 us; speedup 1.0000x reference)
//
#include <hip/hip_runtime.h>
#include <stdint.h>

// ---------------- problem constants ----------------
#define EDIM   300      // hidden/embed dim
#define KPAD   320      // padded K for MFMA GEMMs
#define NG     1200     // 4*EDIM gates
#define NB     64       // batch
#define SENC   64       // encoder steps
#define SDEC   63       // decoder steps
#define ZHV    12016
#define DROWS  4032     // NB*SDEC
#define MPAD   4096
#define SENT   0xFFC1FFC1u   // two bf16 NaNs — unreachable from finite math
#define HXW    10240         // u32 words per h-exchange slot (160 jp x 64 rows)

typedef unsigned short u16;
typedef __attribute__((ext_vector_type(8))) short bf16x8;
typedef __attribute__((ext_vector_type(4))) float f32x4;

static __device__ __forceinline__ u16 f2bf(float f){
  uint32_t u = __builtin_bit_cast(uint32_t, f);
  return (u16)((u + 0x7fffu + ((u >> 16) & 1u)) >> 16);
}
static __device__ __forceinline__ float sigm(float x){ return 1.f/(1.f + __expf(-x)); }
static __device__ __forceinline__ float tanhf_(float x){
  x = fminf(fmaxf(x, -15.f), 15.f);
  float e = __expf(2.f*x);
  return (e - 1.f)/(e + 1.f);
}

// ---------------- workspace init ----------------
__global__ void zero_kernel(float4* p, long n){
  long i = (long)blockIdx.x*blockDim.x + threadIdx.x;
  long st = (long)gridDim.x*blockDim.x;
  float4 z = {0.f,0.f,0.f,0.f};
  for (; i < n; i += st) p[i] = z;
}
__global__ void fill_sent(uint32_t* p, long n){
  long i = (long)blockIdx.x*blockDim.x + threadIdx.x;
  long st = (long)gridDim.x*blockDim.x;
  for (; i < n; i += st) p[i] = SENT;
}

// ---------------- Whh (1200x300) f32 -> MFMA A-fragment tiles bf16 ----------------
// frag = ((slice*4 + gate)*10 + kc); elem (lane*8 + e) = Whh[g*300 + slice*16 + (lane&15)]
//                                                          [kc*32 + (lane>>4)*8 + e], 0-padded.
__global__ void build_wa(const float* __restrict__ W, u16* __restrict__ out){
  int idx = blockIdx.x*blockDim.x + threadIdx.x;
  if (idx >= 20*4*10*512) return;
  int e    = idx & 7;
  int lane = (idx >> 3) & 63;
  int frag = idx >> 9;
  int kc = frag % 10;
  int g  = (frag / 10) & 3;
  int s  = frag / 40;
  int j = s*16 + (lane & 15);
  int k = kc*32 + ((lane >> 4) << 3) + e;
  float f = (j < EDIM && k < EDIM) ? W[(size_t)(g*EDIM + j)*EDIM + k] : 0.f;
  out[idx] = f2bf(f);
}

// ---------------- weight repack: (N x 300) f32 -> (Npad x 320) bf16 ----------------
__global__ void build_b(const float* __restrict__ W, u16* __restrict__ out, int N){
  int idx = blockIdx.x*blockDim.x + threadIdx.x;
  if (idx >= N*EDIM) return;
  int n = idx / EDIM, k = idx - n*EDIM;
  out[(size_t)n*KPAD + k] = f2bf(W[idx]);
}

// ---------------- embeddings -> padded bf16 A operands ----------------
__global__ void embed_en(const int* __restrict__ ids, const float* __restrict__ emb, u16* __restrict__ x){
  int idx = blockIdx.x*blockDim.x + threadIdx.x;
  if (idx >= MPAD*EDIM) return;
  int r = idx / EDIM, k = idx - r*EDIM;
  x[(size_t)r*KPAD + k] = f2bf(emb[(size_t)ids[r]*EDIM + k]);
}
__global__ void embed_zh(const int* __restrict__ zh, const float* __restrict__ emb, u16* __restrict__ x){
  int idx = blockIdx.x*blockDim.x + threadIdx.x;
  if (idx >= DROWS*EDIM) return;
  int r = idx / EDIM, k = idx - r*EDIM;
  int b = r / SDEC, t = r - b*SDEC;
  x[(size_t)r*KPAD + k] = f2bf(emb[(size_t)zh[b*SENC + t]*EDIM + k]);
}

// ---------------- bf16 MFMA GEMM: C[m,n] = sum_k A[m,k]*B[n,k] (+bias[n]) ----------------
#define LDT 40   // LDS row stride in bf16 elems (80 B)
__global__ __launch_bounds__(256) void gemm_nt(const u16* __restrict__ A, const u16* __restrict__ B,
                float* __restrict__ C, int ldc, int Mreal, int Nreal, const float* __restrict__ bias){
  __shared__ __align__(16) u16 As[128*LDT];
  __shared__ __align__(16) u16 Bs[128*LDT];
  int tid = threadIdx.x;
  int lane = tid & 63, wave = tid >> 6;
  int wm = wave >> 1, wn = wave & 1;
  int m0 = blockIdx.y*128, n0 = blockIdx.x*128;
  f32x4 acc[4][4];
  for (int i=0;i<4;i++) for (int j=0;j<4;j++) acc[i][j] = (f32x4){0.f,0.f,0.f,0.f};
  int r16 = lane & 15, kg = lane >> 4;
  for (int kt=0; kt<KPAD/32; kt++){
    int k0 = kt*32;
    for (int c=0;c<2;c++){
      int id = c*256 + tid;            // 0..511
      int row = id >> 2, col = id & 3; // 4 x 16B chunks per 32-k row
      *(uint4*)&As[row*LDT + col*8] = *(const uint4*)&A[(size_t)(m0+row)*KPAD + k0 + col*8];
      *(uint4*)&Bs[row*LDT + col*8] = *(const uint4*)&B[(size_t)(n0+row)*KPAD + k0 + col*8];
    }
    __syncthreads();
    bf16x8 af[4], bfr[4];
    for (int i=0;i<4;i++) af[i]  = *(const bf16x8*)&As[(wm*64 + i*16 + r16)*LDT + kg*8];
    for (int j=0;j<4;j++) bfr[j] = *(const bf16x8*)&Bs[(wn*64 + j*16 + r16)*LDT + kg*8];
    for (int i=0;i<4;i++)
      for (int j=0;j<4;j++)
        acc[i][j] = __builtin_amdgcn_mfma_f32_16x16x32_bf16(af[i], bfr[j], acc[i][j], 0, 0, 0);
    __syncthreads();
  }
  // C/D layout (m89-verified): col = lane&15, row = (lane>>4)*4 + reg
  for (int j=0;j<4;j++){
    int col = n0 + wn*64 + j*16 + r16;
    if (col >= Nreal) continue;
    float bv = bias ? bias[col] : 0.f;
    for (int i=0;i<4;i++){
      int rbase = m0 + wm*64 + i*16 + kg*4;
      for (int r=0;r<4;r++){
        int row = rbase + r;
        if (row < Mreal) C[(size_t)row*ldc + col] = acc[i][j][r] + bv;
      }
    }
  }
}

// ---------------- LSTM recurrence: batched MFMA, weights resident in VGPRs ----------------
// 5 blocks x 4 waves. Wave (block*4+wv) owns j-slice s: j in [s*16, s*16+16) for ALL
// 4 gates and ALL 64 batch rows. gates = Whh (in regs, 160 VGPR) x h(t-1) (LDS B-frags)
// + XIH preload (bias folded). h exchanged cross-block via 4-slot sentinel protocol
// (round-2-proven): producers atomic-store packed 2xbf16 words; consumers spin on
// their copy share against SENT, stage into XOR-swizzled LDS; each lane resets its
// own words of slot (t+2)&3 after poll success (barrier vmcnt-drains order resets
// before later publishes). c stays in lane registers (C-layout: row=batch col,
// j_local=(lane>>4)*4+reg).
__global__ __launch_bounds__(256,1) void recur_mfma(
    const float* __restrict__ Xih, const u16* __restrict__ WA,
    const float* __restrict__ h0, const float* __restrict__ c0,
    uint32_t* hx, u16* seq, float* hfin, float* cfin, int steps)
{
  int tid = threadIdx.x;
  int lane = tid & 63, wv = tid >> 6;
  int s = blockIdx.x*4 + wv;          // j-slice 0..19
  int l15 = lane & 15, lk = lane >> 4;
  int jb = s*16 + lk*4;               // this lane's output j-base (C layout)
  int jp0 = jb >> 1;

  __shared__ __align__(16) u16 hb[64*KPAD];   // h staging, [row][k] bf16, XOR-swizzled
  for (int i = tid; i < 64*KPAD/2; i += 256) ((uint32_t*)hb)[i] = 0;

  // resident A-fragments: wfr[gate][kc], 160 VGPRs
  bf16x8 wfr[4][10];
  #pragma unroll
  for (int g=0; g<4; ++g)
    #pragma unroll
    for (int kc=0; kc<10; ++kc)
      wfr[g][kc] = *(const bf16x8*)&WA[(size_t)((s*4+g)*10 + kc)*512 + lane*8];

  // c init + publish h0 into slot 3
  f32x4 creg[4];
  #pragma unroll
  for (int nt=0; nt<4; ++nt){
    int row = nt*16 + l15;
    float hv4[4];
    #pragma unroll
    for (int r=0; r<4; ++r){
      int j = jb + r;
      creg[nt][r] = (j < EDIM) ? c0[row*EDIM + j] : 0.f;
      hv4[r]      = (j < EDIM) ? h0[row*EDIM + j] : 0.f;
    }
    uint32_t w0 = (uint32_t)f2bf(hv4[0]) | ((uint32_t)f2bf(hv4[1]) << 16);
    uint32_t w1 = (uint32_t)f2bf(hv4[2]) | ((uint32_t)f2bf(hv4[3]) << 16);
    __hip_atomic_store(&hx[3*HXW + jp0*64 + row],     w0, __ATOMIC_RELAXED, __HIP_MEMORY_SCOPE_AGENT);
    __hip_atomic_store(&hx[3*HXW + (jp0+1)*64 + row], w1, __ATOMIC_RELAXED, __HIP_MEMORY_SCOPE_AGENT);
  }
  __syncthreads();

  for (int t=0; t<steps; ++t){
    int sr = (t+3)&3, sw = t&3, sz = (t+2)&3;

    // acc init = XIH (+bias, folded by gemm) — issued early, consumed after barrier
    f32x4 acc[4][4];
    #pragma unroll
    for (int g=0; g<4; ++g)
      #pragma unroll
      for (int nt=0; nt<4; ++nt){
        int row = nt*16 + l15;
        acc[g][nt] = *(const f32x4*)&Xih[(size_t)(row*steps + t)*NG + g*EDIM + jb];
      }

    // copy-poll h(t-1): 38 words per thread (9728 = 64 rows x 152 jp)
    {
      const uint32_t* src = hx + sr*HXW;
      uint32_t vals[38];
      #pragma unroll
      for (int i=0;i<38;++i)
        vals[i] = __hip_atomic_load(&src[tid + i*256], __ATOMIC_RELAXED, __HIP_MEMORY_SCOPE_AGENT);
      #pragma unroll
      for (int i=0;i<38;++i){
        int w = tid + i*256;
        while (vals[i] == SENT)
          vals[i] = __hip_atomic_load(&src[w], __ATOMIC_RELAXED, __HIP_MEMORY_SCOPE_AGENT);
        int row = w & 63, jp = w >> 6;
        int u16i = row*KPAD + ((((jp<<2)) ^ ((row&7)<<4)) >> 1);
        *(uint32_t*)&hb[u16i] = vals[i];
      }
    }
    // recycle: sentinel our own words of the slot holding step t-2 data
    #pragma unroll
    for (int nt=0; nt<4; ++nt){
      int row = nt*16 + l15;
      __hip_atomic_store(&hx[sz*HXW + jp0*64 + row],     SENT, __ATOMIC_RELAXED, __HIP_MEMORY_SCOPE_AGENT);
      __hip_atomic_store(&hx[sz*HXW + (jp0+1)*64 + row], SENT, __ATOMIC_RELAXED, __HIP_MEMORY_SCOPE_AGENT);
    }
    __syncthreads();   // hb staged; resets/stores drained (vmcnt 0)

    // gates += Whh x h : 160 MFMA
    #pragma unroll
    for (int kc=0; kc<10; ++kc){
      bf16x8 hf[4];
      #pragma unroll
      for (int nt=0; nt<4; ++nt){
        int row = nt*16 + l15;
        int kbyte = kc*64 + (lk<<4);
        hf[nt] = *(const bf16x8*)&hb[row*KPAD + ((kbyte ^ ((row&7)<<4)) >> 1)];
      }
      #pragma unroll
      for (int g=0; g<4; ++g)
        #pragma unroll
        for (int nt=0; nt<4; ++nt)
          acc[g][nt] = __builtin_amdgcn_mfma_f32_16x16x32_bf16(wfr[g][kc], hf[nt], acc[g][nt], 0, 0, 0);
    }

    // activation + publish h(t) + seq/finals
    #pragma unroll
    for (int nt=0; nt<4; ++nt){
      int row = nt*16 + l15;
      float hv4[4];
      #pragma unroll
      for (int r=0; r<4; ++r){
        float gi = acc[0][nt][r], gf = acc[1][nt][r];
        float gg = acc[2][nt][r], go = acc[3][nt][r];
        float c = sigm(gf)*creg[nt][r] + sigm(gi)*tanhf_(gg);
        creg[nt][r] = c;
        hv4[r] = sigm(go)*tanhf_(c);
      }
      uint32_t w0 = (uint32_t)f2bf(hv4[0]) | ((uint32_t)f2bf(hv4[1]) << 16);
      uint32_t w1 = (uint32_t)f2bf(hv4[2]) | ((uint32_t)f2bf(hv4[3]) << 16);
      __hip_atomic_store(&hx[sw*HXW + jp0*64 + row],     w0, __ATOMIC_RELAXED, __HIP_MEMORY_SCOPE_AGENT);
      __hip_atomic_store(&hx[sw*HXW + (jp0+1)*64 + row], w1, __ATOMIC_RELAXED, __HIP_MEMORY_SCOPE_AGENT);
      if (seq){
        size_t sb = (size_t)(row*steps + t)*KPAD + jb;
        if (jb + 3 < EDIM){
          uint2 q; q.x = w0; q.y = w1;
          *(uint2*)&seq[sb] = q;      // 4 bf16, 8B aligned (jb%4==0)
        } else {
          #pragma unroll
          for (int r=0; r<4; ++r) if (jb + r < EDIM) seq[sb + r] = f2bf(hv4[r]);
        }
      }
      if (t == steps-1 && hfin){
        #pragma unroll
        for (int r=0; r<4; ++r) if (jb + r < EDIM){
          hfin[row*EDIM + jb + r] = hv4[r];
          cfin[row*EDIM + jb + r] = creg[nt][r];
        }
      }
    }
    __syncthreads();   // hb reads done before next iteration's copy overwrites
  }
}

// ---------------- fused log_softmax (in-place on d_out) + masked NLL ----------------
__global__ __launch_bounds__(256) void lsm_loss(float* __restrict__ out, const int* __restrict__ zh,
                                                float* __restrict__ lacc){
  int row = blockIdx.x;
  int tid = threadIdx.x;
  __shared__ float buf[ZHV];
  __shared__ float red[8];
  float* p = out + (size_t)row*ZHV;
  float m = -1e30f;
  for (int i=tid; i<ZHV; i+=256){ float v = p[i]; buf[i] = v; m = fmaxf(m, v); }
  for (int off=32; off; off>>=1) m = fmaxf(m, __shfl_xor(m, off));
  if ((tid&63)==0) red[tid>>6] = m;
  __syncthreads();
  m = fmaxf(fmaxf(red[0],red[1]), fmaxf(red[2],red[3]));
  float s = 0.f;
  for (int i=tid; i<ZHV; i+=256) s += __expf(buf[i]-m);
  for (int off=32; off; off>>=1) s += __shfl_xor(s, off);
  if ((tid&63)==0) red[4+(tid>>6)] = s;
  __syncthreads();
  s = red[4]+red[5]+red[6]+red[7];
  float lse = m + __logf(s);
  for (int i=tid; i<ZHV; i+=256) p[i] = buf[i] - lse;
  if (tid == 0){
    int b = row / SDEC, t = row - b*SDEC;
    int tgt = zh[b*SENC + t + 1];
    if (tgt != 0){
      atomicAdd(&lacc[0], -(buf[tgt] - lse));
      atomicAdd(&lacc[1], 1.0f);
    }
  }
}

__global__ void fin_loss(float* out, const float* lacc){
  out[(size_t)DROWS*ZHV] = lacc[0]/lacc[1];
}

// ---------------- host ----------------
extern "C" void kernel_launch(void* const* d_in, const int* in_sizes, int n_in,
                              void* d_out, int out_size, void* d_ws, size_t ws_size,
                              hipStream_t stream){
  const int*   en_in   = (const int*)d_in[0];
  const int*   zh_in   = (const int*)d_in[1];
  const float* en_emb  = (const float*)d_in[2];
  const float* zh_emb  = (const float*)d_in[3];
  const float* enc_Wih = (const float*)d_in[4];
  const float* enc_Whh = (const float*)d_in[5];
  const float* enc_b   = (const float*)d_in[6];
  const float* dec_Wih = (const float*)d_in[7];
  const float* dec_Whh = (const float*)d_in[8];
  const float* dec_b   = (const float*)d_in[9];
  const float* fc_W    = (const float*)d_in[10];
  const float* fc_b    = (const float*)d_in[11];
  float* out = (float*)d_out;
  char* ws = (char*)d_ws;

  size_t o = 0;
  auto alloc = [&](size_t b){ size_t r = o; o = (o + b + 255) & ~(size_t)255; return r; };
  size_t wa[4], wih[4];
  for (int i=0;i<4;i++) wa[i]  = alloc((size_t)20*4*10*512*2);  // MFMA A-frag Whh bf16
  for (int i=0;i<4;i++) wih[i] = alloc((size_t)1280*KPAD*2);    // Wih as B operand
  size_t fcw  = alloc((size_t)12032*KPAD*2);
  size_t xen  = alloc((size_t)MPAD*KPAD*2);
  size_t xl1e = alloc((size_t)MPAD*KPAD*2);
  size_t xzh  = alloc((size_t)MPAD*KPAD*2);
  size_t xl1d = alloc((size_t)MPAD*KPAD*2);
  size_t xl2d = alloc((size_t)MPAD*KPAD*2);
  size_t xih  = alloc(((size_t)MPAD*NG + 64)*4);   // +64 floats: padded-slice overread
  size_t hxo  = alloc((size_t)4*4*HXW*4);          // 4 layers x 4 slots x 40KB
  size_t hfin = alloc((size_t)2*NB*EDIM*4);
  size_t cfin = alloc((size_t)2*NB*EDIM*4);
  size_t hz   = alloc((size_t)NB*EDIM*4);
  size_t lac  = alloc(256);
  size_t used = o;
  if (ws_size < used) return;  // fail loudly (output stays poisoned)

  zero_kernel<<<2048,256,0,stream>>>((float4*)ws, (long)(used/16));
  fill_sent<<<1024,256,0,stream>>>((uint32_t*)(ws+hxo), (long)4*4*HXW);

  for (int l=0;l<2;l++){
    build_wa<<<1600,256,0,stream>>>(enc_Whh + (size_t)l*NG*EDIM, (u16*)(ws+wa[l]));
    build_wa<<<1600,256,0,stream>>>(dec_Whh + (size_t)l*NG*EDIM, (u16*)(ws+wa[2+l]));
    build_b<<<1407,256,0,stream>>>(enc_Wih + (size_t)l*NG*EDIM, (u16*)(ws+wih[l]),   NG);
    build_b<<<1407,256,0,stream>>>(dec_Wih + (size_t)l*NG*EDIM, (u16*)(ws+wih[2+l]), NG);
  }
  build_b<<<(ZHV*EDIM+255)/256,256,0,stream>>>(fc_W, (u16*)(ws+fcw), ZHV);
  embed_en<<<(MPAD*EDIM+255)/256,256,0,stream>>>(en_in, en_emb, (u16*)(ws+xen));
  embed_zh<<<(DROWS*EDIM+255)/256,256,0,stream>>>(zh_in, zh_emb, (u16*)(ws+xzh));

  float* XIH = (float*)(ws+xih);
  uint32_t* HX = (uint32_t*)(ws+hxo);
  float* LAC = (float*)(ws+lac);
  float* HF  = (float*)(ws+hfin);
  float* CF  = (float*)(ws+cfin);
  float* HZ  = (float*)(ws+hz);

  // encoder layer 1  (LSTM bias folded into XIH via gemm bias)
  gemm_nt<<<dim3(10,32),256,0,stream>>>((u16*)(ws+xen), (u16*)(ws+wih[0]), XIH, NG, MPAD, NG, enc_b);
  recur_mfma<<<5,256,0,stream>>>(XIH, (u16*)(ws+wa[0]), HZ, HZ, HX, (u16*)(ws+xl1e), HF, CF, SENC);
  // encoder layer 2 (hidden sequence unused; only finals kept)
  gemm_nt<<<dim3(10,32),256,0,stream>>>((u16*)(ws+xl1e), (u16*)(ws+wih[1]), XIH, NG, MPAD, NG, enc_b+NG);
  recur_mfma<<<5,256,0,stream>>>(XIH, (u16*)(ws+wa[1]), HZ, HZ, HX+(size_t)4*HXW, nullptr, HF+NB*EDIM, CF+NB*EDIM, SENC);
  // decoder layer 1
  gemm_nt<<<dim3(10,32),256,0,stream>>>((u16*)(ws+xzh), (u16*)(ws+wih[2]), XIH, NG, MPAD, NG, dec_b);
  recur_mfma<<<5,256,0,stream>>>(XIH, (u16*)(ws+wa[2]), HF, CF, HX+(size_t)8*HXW, (u16*)(ws+xl1d), nullptr, nullptr, SDEC);
  // decoder layer 2
  gemm_nt<<<dim3(10,32),256,0,stream>>>((u16*)(ws+xl1d), (u16*)(ws+wih[3]), XIH, NG, MPAD, NG, dec_b+NG);
  recur_mfma<<<5,256,0,stream>>>(XIH, (u16*)(ws+wa[3]), HF+NB*EDIM, CF+NB*EDIM, HX+(size_t)12*HXW, (u16*)(ws+xl2d), nullptr, nullptr, SDEC);
  // FC head -> logits straight into d_out
  gemm_nt<<<dim3(94,32),256,0,stream>>>((u16*)(ws+xl2d), (u16*)(ws+fcw), out, ZHV, DROWS, ZHV, fc_b);
  // in-place log_softmax + masked NLL
  lsm_loss<<<DROWS,256,0,stream>>>(out, zh_in, LAC);
  fin_loss<<<1,1,0,stream>>>(out, LAC);
}